// Round 21
// baseline (182.440 us; speedup 1.0000x reference)
//
#include <hip/hip_runtime.h>

// Problem constants (fixed by setup_inputs)
#define B_ 4
#define C_ 256
#define N_ 4096   // 64*64 spatial
#define D_ 8      // QK_DIM

typedef float f32x4 __attribute__((ext_vector_type(4)));
typedef __bf16 bf16x8 __attribute__((ext_vector_type(8)));

union U16 {
  bf16x8 v;
  unsigned short u[8];
  uint4 q;
};

__device__ inline unsigned short f2bf(float f) {
  unsigned int u = __float_as_uint(f);
  u = (u + 0x7FFFu + ((u >> 16) & 1u)) >> 16;  // RNE
  return (unsigned short)u;
}

#define AS1 __attribute__((address_space(1)))
#define AS3 __attribute__((address_space(3)))
__device__ __forceinline__ void g2l16(const void* g, void* l) {
  // async global->LDS DMA, 16B/lane; LDS dest = wave-uniform base + lane*16
  __builtin_amdgcn_global_load_lds((AS1 const void*)g, (AS3 void*)l, 16, 0, 0);
}

// ---------------------------------------------------------------------------
// K1: pq[b][n][d] = Wq[d,:]·q[b,:,n] + bq[d]   (B,N,8) d-contiguous
//     pk[b][d][n] = Wk[d,:]·k[b,:,n] + bk[d]   (B,8,N) n-contiguous
// ---------------------------------------------------------------------------
__global__ void __launch_bounds__(256) k_pqk(
    const float* __restrict__ q, const float* __restrict__ k,
    const float* __restrict__ Wq, const float* __restrict__ bq,
    const float* __restrict__ Wk, const float* __restrict__ bk,
    float* __restrict__ pq_g, float* __restrict__ pk_g) {
  int b = blockIdx.y, n0 = blockIdx.x * 64;
  int t = threadIdx.x, nl = t & 63, sub = t >> 6;  // sub uniform per wave
  int n = n0 + nl;
  float aq[D_], ak[D_];
#pragma unroll
  for (int d = 0; d < D_; ++d) { aq[d] = 0.f; ak[d] = 0.f; }
  const float* qp = q + ((size_t)(b * C_ + sub * 64)) * N_ + n;
  const float* kp = k + ((size_t)(b * C_ + sub * 64)) * N_ + n;
  for (int cc = 0; cc < 64; ++cc) {
    int c = sub * 64 + cc;
    float qv = qp[(size_t)cc * N_];
    float kv = kp[(size_t)cc * N_];
#pragma unroll
    for (int d = 0; d < D_; ++d) {
      aq[d] = fmaf(Wq[d * C_ + c], qv, aq[d]);
      ak[d] = fmaf(Wk[d * C_ + c], kv, ak[d]);
    }
  }
  __shared__ float red[4][64][16];
#pragma unroll
  for (int d = 0; d < D_; ++d) { red[sub][nl][d] = aq[d]; red[sub][nl][8 + d] = ak[d]; }
  __syncthreads();
  if (t < 64) {
#pragma unroll
    for (int d = 0; d < D_; ++d) {
      float s = red[0][t][d] + red[1][t][d] + red[2][t][d] + red[3][t][d] + bq[d];
      pq_g[((size_t)b * N_ + n0 + t) * D_ + d] = s;
      float s2 = red[0][t][8 + d] + red[1][t][8 + d] + red[2][t][8 + d] + red[3][t][8 + d] + bk[d];
      pk_g[((size_t)b * D_ + d) * N_ + n0 + t] = s2;
    }
  }
}

// ---------------------------------------------------------------------------
// K2: pv[b][e][n] = Wv[e,:]·x[b,:,n] + bv[e], stored bf16 in (B,C,N).
// ---------------------------------------------------------------------------
__global__ void __launch_bounds__(256) k_pv(
    const float* __restrict__ x, const float* __restrict__ Wv,
    const float* __restrict__ bv, unsigned short* __restrict__ pv_g) {
  int b = blockIdx.y, n0 = blockIdx.x * 64;
  int t = threadIdx.x, lane = t & 63, w = t >> 6;
  __shared__ unsigned short xs[64][264];  // [n][c]
  {
    int nl = t & 63, sub = t >> 6;
    for (int i = 0; i < 64; ++i) {
      int c = i * 4 + sub;
      float xv = x[((size_t)(b * C_ + c)) * N_ + n0 + nl];
      xs[nl][c] = f2bf(xv);
    }
  }
  __syncthreads();
  int e0 = w * 64;
  f32x4 acc[4][4];
#pragma unroll
  for (int mf = 0; mf < 4; ++mf)
#pragma unroll
    for (int nf = 0; nf < 4; ++nf) acc[mf][nf] = (f32x4)0.f;

  int rsel = lane & 15, koff = (lane >> 4) * 8;
  for (int kc = 0; kc < 8; ++kc) {
    int cbase = kc * 32 + koff;
    U16 afr[4];
#pragma unroll
    for (int mf = 0; mf < 4; ++mf) {
      const float* wp = Wv + (size_t)(e0 + mf * 16 + rsel) * C_ + cbase;
      float4 w0 = *(const float4*)wp;
      float4 w1 = *(const float4*)(wp + 4);
      afr[mf].u[0] = f2bf(w0.x); afr[mf].u[1] = f2bf(w0.y);
      afr[mf].u[2] = f2bf(w0.z); afr[mf].u[3] = f2bf(w0.w);
      afr[mf].u[4] = f2bf(w1.x); afr[mf].u[5] = f2bf(w1.y);
      afr[mf].u[6] = f2bf(w1.z); afr[mf].u[7] = f2bf(w1.w);
    }
    U16 bfr[4];
#pragma unroll
    for (int nf = 0; nf < 4; ++nf)
      bfr[nf].q = *(const uint4*)&xs[nf * 16 + rsel][cbase];
#pragma unroll
    for (int mf = 0; mf < 4; ++mf)
#pragma unroll
      for (int nf = 0; nf < 4; ++nf)
        acc[mf][nf] = __builtin_amdgcn_mfma_f32_16x16x32_bf16(afr[mf].v, bfr[nf].v, acc[mf][nf], 0, 0, 0);
  }
  int rowsub = (lane >> 4) * 4;
#pragma unroll
  for (int mf = 0; mf < 4; ++mf) {
#pragma unroll
    for (int nf = 0; nf < 4; ++nf) {
      int n = n0 + nf * 16 + rsel;
#pragma unroll
      for (int j = 0; j < 4; ++j) {
        int e = e0 + mf * 16 + rowsub + j;
        float v = acc[mf][nf][j] + bv[e];
        pv_g[((size_t)(b * C_ + e)) * N_ + n] = f2bf(v);
      }
    }
  }
}

// ---------------------------------------------------------------------------
// K3: rinv[b][n] = 1 / sum_m exp(energy[b][n][m]).  [round-1 verified]
// ---------------------------------------------------------------------------
__global__ void __launch_bounds__(256) k_rowsum(
    const float* __restrict__ pq_g, const float* __restrict__ pk_g,
    float* __restrict__ rinv_g) {
  int b = blockIdx.y, n0 = blockIdx.x * 32;
  int t = threadIdx.x, lane = t & 63, w = t >> 6;
  int r0 = n0 + w * 8;
  float pqr[8][D_];
#pragma unroll
  for (int r = 0; r < 8; ++r) {
    const float4* pp = (const float4*)(pq_g + ((size_t)b * N_ + r0 + r) * D_);
    float4 a = pp[0], c4 = pp[1];
    pqr[r][0] = a.x; pqr[r][1] = a.y; pqr[r][2] = a.z; pqr[r][3] = a.w;
    pqr[r][4] = c4.x; pqr[r][5] = c4.y; pqr[r][6] = c4.z; pqr[r][7] = c4.w;
  }
  float s[8];
#pragma unroll
  for (int r = 0; r < 8; ++r) s[r] = 0.f;
  const float* pkb = pk_g + (size_t)b * D_ * N_;
  for (int tt = 0; tt < 64; ++tt) {
    int m = tt * 64 + lane;
    float pkr[D_];
#pragma unroll
    for (int d = 0; d < D_; ++d) pkr[d] = pkb[(size_t)d * N_ + m];
#pragma unroll
    for (int r = 0; r < 8; ++r) {
      float e = pqr[r][0] * pkr[0];
#pragma unroll
      for (int d = 1; d < D_; ++d) e = fmaf(pqr[r][d], pkr[d], e);
      s[r] += __expf(e);
    }
  }
#pragma unroll
  for (int r = 0; r < 8; ++r) {
    float v = s[r];
    for (int off = 32; off; off >>= 1) v += __shfl_xor(v, off);
    s[r] = v;
  }
  if (lane == 0) {
#pragma unroll
    for (int r = 0; r < 8; ++r) rinv_g[(size_t)b * N_ + r0 + r] = 1.0f / s[r];
  }
}

// ---------------------------------------------------------------------------
// K4 FUSED v3 (store-MLP fix): phase A vectorized — each lane computes 4
// consecutive m for 2 rows (2 passes) instead of 1 m for 8 rows. Attention
// stores become 2x f32x4 NT per wave-iter (1KB/instr, 4x outstanding bytes)
// instead of 8 scalar; pk prefetch is 8x float4; asl writes 2x 8B. Same
// FLOPs, ~4x store MLP — attacks the measured ~3.6B/cyc/CU write ceiling
// (r18/r20: 8 waves x 2KB outstanding; k_attn's 2x waves gave 2.3x BW).
// Also adds the post-MFMA barrier (closes the latent pvs overwrite race).
// Everything else identical to round-18/20.
// ---------------------------------------------------------------------------
__global__ void __launch_bounds__(256, 2) k_fused(
    const float* __restrict__ pq_g, const float* __restrict__ pk_g,
    const float* __restrict__ rinv_g, const unsigned short* __restrict__ pv_g,
    const float* __restrict__ x, const float* __restrict__ gamma,
    float* __restrict__ out_g, float* __restrict__ attn_g) {
  int bx = blockIdx.x;
  int b = bx & 3, grp = bx >> 2;
  int n0 = grp * 32;
  int t = threadIdx.x, lane = t & 63, w = t >> 6;
  int rsel = lane & 15, g = lane >> 4, koff = g * 8;
  int c0 = w * 64;
  int r0 = n0 + w * 8;           // phase-A rows for this wave
  int l15 = lane & 15, lg = lane >> 4;  // m-sub(x4), row-sub

  __shared__ unsigned short pvs[2][256][64];  // 64KB, slot-swizzled content
  __shared__ unsigned short asl[2][32][72];   // 9KB attn bf16, pad 72

  // per-lane row data: rows {lg, 4+lg} of this wave's 8
  float pqr2[2][D_], rinv2[2];
#pragma unroll
  for (int p = 0; p < 2; ++p) {
    int row = r0 + p * 4 + lg;
    const float4* pp = (const float4*)(pq_g + ((size_t)b * N_ + row) * D_);
    float4 a = pp[0], c4 = pp[1];
    pqr2[p][0] = a.x; pqr2[p][1] = a.y; pqr2[p][2] = a.z; pqr2[p][3] = a.w;
    pqr2[p][4] = c4.x; pqr2[p][5] = c4.y; pqr2[p][6] = c4.z; pqr2[p][7] = c4.w;
    rinv2[p] = rinv_g[(size_t)b * N_ + row];
  }

  const float* pkb = pk_g + (size_t)b * D_ * N_;
  const unsigned short* pvb = pv_g + (size_t)b * C_ * N_;
  // per-lane attention row pointers (row p*4+lg), m column base l15*4
  float* attb0 = attn_g + ((size_t)b * N_ + r0 + 0 + lg) * N_ + l15 * 4;
  float* attb1 = attn_g + ((size_t)b * N_ + r0 + 4 + lg) * N_ + l15 * 4;

  f32x4 acc[2][4];
#pragma unroll
  for (int mf = 0; mf < 2; ++mf)
#pragma unroll
    for (int cf = 0; cf < 4; ++cf) acc[mf][cf] = (f32x4)0.f;

  // pv staging: wave w's 64 c-rows; LDS linear, source XOR-swizzled (verified)
#define STAGEPV(dstbuf, M0)                                                   \
  {                                                                           \
    _Pragma("unroll")                                                         \
    for (int i = 0; i < 8; ++i) {                                             \
      int c = c0 + i * 8 + (lane >> 3);                                       \
      int seg = lane & 7;                                                     \
      g2l16(pvb + (size_t)c * N_ + (M0) + ((seg ^ (c & 7)) << 3),             \
            &pvs[dstbuf][c0 + i * 8][0]);                                     \
    }                                                                         \
  }

  // prologue: tile 0 pv DMAs + tile 0 pk float4 regs
  STAGEPV(0, 0)
  f32x4 pkr4[D_];
#pragma unroll
  for (int d = 0; d < D_; ++d)
    pkr4[d] = *(const f32x4*)(pkb + (size_t)d * N_ + l15 * 4);

  int cur = 0;
  for (int tt = 0; tt < 64; ++tt) {
    int m0 = tt * 64;
    bool more = (tt + 1 < 64);
    // ---- issue tile t+1: pv DMAs then pk float4 loads ----
    if (more) STAGEPV(cur ^ 1, m0 + 64)
    f32x4 pkn4[D_];
    if (more) {
#pragma unroll
      for (int d = 0; d < D_; ++d)
        pkn4[d] = *(const f32x4*)(pkb + (size_t)d * N_ + m0 + 64 + l15 * 4);
    }
    // ---- phase A: 2 passes x (row p*4+lg, m = m0 + l15*4 .. +4) ----
#pragma unroll
    for (int p = 0; p < 2; ++p) {
      f32x4 e = pqr2[p][0] * pkr4[0];
#pragma unroll
      for (int d = 1; d < D_; ++d) e += pqr2[p][d] * pkr4[d];
      f32x4 av;
#pragma unroll
      for (int j = 0; j < 4; ++j) av[j] = __expf(e[j]) * rinv2[p];
      __builtin_nontemporal_store(av, (f32x4*)((p ? attb1 : attb0) + m0));
      unsigned int lo = (unsigned)f2bf(av[0]) | ((unsigned)f2bf(av[1]) << 16);
      unsigned int hi = (unsigned)f2bf(av[2]) | ((unsigned)f2bf(av[3]) << 16);
      uint2 u2; u2.x = lo; u2.y = hi;
      *(uint2*)&asl[cur][w * 8 + p * 4 + lg][l15 * 4] = u2;
    }
    // ---- asl visible; DMA(t) already drained by phase-A's pk wait ----
    asm volatile("s_waitcnt lgkmcnt(0)" ::: "memory");
    __builtin_amdgcn_s_barrier();
    // ---- MFMA: 32 n x 64 c over K=64 from asl[cur] + pvs[cur] ----
    {
      U16 afr[2][2], bfr[2][4];
#pragma unroll
      for (int kf = 0; kf < 2; ++kf) {
#pragma unroll
        for (int mf = 0; mf < 2; ++mf)
          afr[kf][mf].q = *(const uint4*)&asl[cur][mf * 16 + rsel][kf * 32 + koff];
#pragma unroll
        for (int cf = 0; cf < 4; ++cf) {
          int c = c0 + cf * 16 + rsel;
          int sg = kf * 4 + g;
          bfr[kf][cf].q = *(const uint4*)&pvs[cur][c][(sg ^ (c & 7)) * 8];
        }
      }
#pragma unroll
      for (int kf = 0; kf < 2; ++kf)
#pragma unroll
        for (int mf = 0; mf < 2; ++mf)
#pragma unroll
          for (int cf = 0; cf < 4; ++cf)
            acc[mf][cf] = __builtin_amdgcn_mfma_f32_16x16x32_bf16(
                afr[kf][mf].v, bfr[kf][cf].v, acc[mf][cf], 0, 0, 0);
    }
    // ---- all waves done reading pvs[cur]/asl[cur] before next overwrite ----
    __builtin_amdgcn_s_barrier();
#pragma unroll
    for (int d = 0; d < D_; ++d) pkr4[d] = pkn4[d];
    cur ^= 1;
  }
#undef STAGEPV
  // epilogue: out = gamma*acc + x.  D layout: col(lane&15)=c-frag, row=g*4+j
  float gm = gamma[0];
  int rowsub = g * 4;
#pragma unroll
  for (int mf = 0; mf < 2; ++mf) {
#pragma unroll
    for (int cf = 0; cf < 4; ++cf) {
      int c = c0 + cf * 16 + rsel;
      int nrow = n0 + mf * 16 + rowsub;
      const float4 xv = *(const float4*)(x + ((size_t)(b * C_ + c)) * N_ + nrow);
      float4 o;
      o.x = gm * acc[mf][cf][0] + xv.x;
      o.y = gm * acc[mf][cf][1] + xv.y;
      o.z = gm * acc[mf][cf][2] + xv.z;
      o.w = gm * acc[mf][cf][3] + xv.w;
      *(float4*)(out_g + ((size_t)(b * C_ + c)) * N_ + nrow) = o;
    }
  }
}

extern "C" void kernel_launch(void* const* d_in, const int* in_sizes, int n_in,
                              void* d_out, int out_size, void* d_ws, size_t ws_size,
                              hipStream_t stream) {
  const float* x  = (const float*)d_in[0];
  const float* k  = (const float*)d_in[1];
  const float* q  = (const float*)d_in[2];
  const float* Wq = (const float*)d_in[3];
  const float* bq = (const float*)d_in[4];
  const float* Wk = (const float*)d_in[5];
  const float* bk = (const float*)d_in[6];
  const float* Wv = (const float*)d_in[7];
  const float* bv = (const float*)d_in[8];
  const float* gamma = (const float*)d_in[9];

  float* out_g  = (float*)d_out;
  float* attn_g = out_g + (size_t)B_ * C_ * N_;  // attention starts after out

  // workspace layout (~9.2 MB): pq 512KB | pk 512KB | rinv 64KB | pv 8MB
  char* ws = (char*)d_ws;
  float* pq_g = (float*)ws;
  float* pk_g = (float*)(ws + (1u << 19));
  float* rinv_g = (float*)(ws + (1u << 20));
  unsigned short* pv_g = (unsigned short*)(ws + (1u << 20) + (1u << 17));

  k_pqk<<<dim3(64, B_), 256, 0, stream>>>(q, k, Wq, bq, Wk, bk, pq_g, pk_g);
  k_pv<<<dim3(64, B_), 256, 0, stream>>>(x, Wv, bv, pv_g);
  k_rowsum<<<dim3(128, B_), 256, 0, stream>>>(pq_g, pk_g, rinv_g);
  k_fused<<<dim3(512), 256, 0, stream>>>(pq_g, pk_g, rinv_g, pv_g, x, gamma, out_g, attn_g);
}

// Round 22
// 160.667 us; speedup vs baseline: 1.1355x; 1.1355x over previous
//
#include <hip/hip_runtime.h>

// Problem constants (fixed by setup_inputs)
#define B_ 4
#define C_ 256
#define N_ 4096   // 64*64 spatial
#define D_ 8      // QK_DIM

typedef float f32x4 __attribute__((ext_vector_type(4)));
typedef __bf16 bf16x8 __attribute__((ext_vector_type(8)));

union U16 {
  bf16x8 v;
  unsigned short u[8];
  uint4 q;
};

__device__ inline unsigned short f2bf(float f) {
  unsigned int u = __float_as_uint(f);
  u = (u + 0x7FFFu + ((u >> 16) & 1u)) >> 16;  // RNE
  return (unsigned short)u;
}

#define AS1 __attribute__((address_space(1)))
#define AS3 __attribute__((address_space(3)))
__device__ __forceinline__ void g2l16(const void* g, void* l) {
  // async global->LDS DMA, 16B/lane; LDS dest = wave-uniform base + lane*16
  __builtin_amdgcn_global_load_lds((AS1 const void*)g, (AS3 void*)l, 16, 0, 0);
}

// ---------------------------------------------------------------------------
// K1: pq[b][n][d] = Wq[d,:]·q[b,:,n] + bq[d]   (B,N,8) d-contiguous
//     pk[b][d][n] = Wk[d,:]·k[b,:,n] + bk[d]   (B,8,N) n-contiguous
// ---------------------------------------------------------------------------
__global__ void __launch_bounds__(256) k_pqk(
    const float* __restrict__ q, const float* __restrict__ k,
    const float* __restrict__ Wq, const float* __restrict__ bq,
    const float* __restrict__ Wk, const float* __restrict__ bk,
    float* __restrict__ pq_g, float* __restrict__ pk_g) {
  int b = blockIdx.y, n0 = blockIdx.x * 64;
  int t = threadIdx.x, nl = t & 63, sub = t >> 6;  // sub uniform per wave
  int n = n0 + nl;
  float aq[D_], ak[D_];
#pragma unroll
  for (int d = 0; d < D_; ++d) { aq[d] = 0.f; ak[d] = 0.f; }
  const float* qp = q + ((size_t)(b * C_ + sub * 64)) * N_ + n;
  const float* kp = k + ((size_t)(b * C_ + sub * 64)) * N_ + n;
  for (int cc = 0; cc < 64; ++cc) {
    int c = sub * 64 + cc;
    float qv = qp[(size_t)cc * N_];
    float kv = kp[(size_t)cc * N_];
#pragma unroll
    for (int d = 0; d < D_; ++d) {
      aq[d] = fmaf(Wq[d * C_ + c], qv, aq[d]);
      ak[d] = fmaf(Wk[d * C_ + c], kv, ak[d]);
    }
  }
  __shared__ float red[4][64][16];
#pragma unroll
  for (int d = 0; d < D_; ++d) { red[sub][nl][d] = aq[d]; red[sub][nl][8 + d] = ak[d]; }
  __syncthreads();
  if (t < 64) {
#pragma unroll
    for (int d = 0; d < D_; ++d) {
      float s = red[0][t][d] + red[1][t][d] + red[2][t][d] + red[3][t][d] + bq[d];
      pq_g[((size_t)b * N_ + n0 + t) * D_ + d] = s;
      float s2 = red[0][t][8 + d] + red[1][t][8 + d] + red[2][t][8 + d] + red[3][t][8 + d] + bk[d];
      pk_g[((size_t)b * D_ + d) * N_ + n0 + t] = s2;
    }
  }
}

// ---------------------------------------------------------------------------
// K2: pv[b][e][n] = Wv[e,:]·x[b,:,n] + bv[e], stored bf16 in (B,C,N).
// ---------------------------------------------------------------------------
__global__ void __launch_bounds__(256) k_pv(
    const float* __restrict__ x, const float* __restrict__ Wv,
    const float* __restrict__ bv, unsigned short* __restrict__ pv_g) {
  int b = blockIdx.y, n0 = blockIdx.x * 64;
  int t = threadIdx.x, lane = t & 63, w = t >> 6;
  __shared__ unsigned short xs[64][264];  // [n][c]
  {
    int nl = t & 63, sub = t >> 6;
    for (int i = 0; i < 64; ++i) {
      int c = i * 4 + sub;
      float xv = x[((size_t)(b * C_ + c)) * N_ + n0 + nl];
      xs[nl][c] = f2bf(xv);
    }
  }
  __syncthreads();
  int e0 = w * 64;
  f32x4 acc[4][4];
#pragma unroll
  for (int mf = 0; mf < 4; ++mf)
#pragma unroll
    for (int nf = 0; nf < 4; ++nf) acc[mf][nf] = (f32x4)0.f;

  int rsel = lane & 15, koff = (lane >> 4) * 8;
  for (int kc = 0; kc < 8; ++kc) {
    int cbase = kc * 32 + koff;
    U16 afr[4];
#pragma unroll
    for (int mf = 0; mf < 4; ++mf) {
      const float* wp = Wv + (size_t)(e0 + mf * 16 + rsel) * C_ + cbase;
      float4 w0 = *(const float4*)wp;
      float4 w1 = *(const float4*)(wp + 4);
      afr[mf].u[0] = f2bf(w0.x); afr[mf].u[1] = f2bf(w0.y);
      afr[mf].u[2] = f2bf(w0.z); afr[mf].u[3] = f2bf(w0.w);
      afr[mf].u[4] = f2bf(w1.x); afr[mf].u[5] = f2bf(w1.y);
      afr[mf].u[6] = f2bf(w1.z); afr[mf].u[7] = f2bf(w1.w);
    }
    U16 bfr[4];
#pragma unroll
    for (int nf = 0; nf < 4; ++nf)
      bfr[nf].q = *(const uint4*)&xs[nf * 16 + rsel][cbase];
#pragma unroll
    for (int mf = 0; mf < 4; ++mf)
#pragma unroll
      for (int nf = 0; nf < 4; ++nf)
        acc[mf][nf] = __builtin_amdgcn_mfma_f32_16x16x32_bf16(afr[mf].v, bfr[nf].v, acc[mf][nf], 0, 0, 0);
  }
  int rowsub = (lane >> 4) * 4;
#pragma unroll
  for (int mf = 0; mf < 4; ++mf) {
#pragma unroll
    for (int nf = 0; nf < 4; ++nf) {
      int n = n0 + nf * 16 + rsel;
#pragma unroll
      for (int j = 0; j < 4; ++j) {
        int e = e0 + mf * 16 + rowsub + j;
        float v = acc[mf][nf][j] + bv[e];
        pv_g[((size_t)(b * C_ + e)) * N_ + n] = f2bf(v);
      }
    }
  }
}

// ---------------------------------------------------------------------------
// K3: rinv[b][n] = 1 / sum_m exp(energy[b][n][m]).  [round-1 verified]
// ---------------------------------------------------------------------------
__global__ void __launch_bounds__(256) k_rowsum(
    const float* __restrict__ pq_g, const float* __restrict__ pk_g,
    float* __restrict__ rinv_g) {
  int b = blockIdx.y, n0 = blockIdx.x * 32;
  int t = threadIdx.x, lane = t & 63, w = t >> 6;
  int r0 = n0 + w * 8;
  float pqr[8][D_];
#pragma unroll
  for (int r = 0; r < 8; ++r) {
    const float4* pp = (const float4*)(pq_g + ((size_t)b * N_ + r0 + r) * D_);
    float4 a = pp[0], c4 = pp[1];
    pqr[r][0] = a.x; pqr[r][1] = a.y; pqr[r][2] = a.z; pqr[r][3] = a.w;
    pqr[r][4] = c4.x; pqr[r][5] = c4.y; pqr[r][6] = c4.z; pqr[r][7] = c4.w;
  }
  float s[8];
#pragma unroll
  for (int r = 0; r < 8; ++r) s[r] = 0.f;
  const float* pkb = pk_g + (size_t)b * D_ * N_;
  for (int tt = 0; tt < 64; ++tt) {
    int m = tt * 64 + lane;
    float pkr[D_];
#pragma unroll
    for (int d = 0; d < D_; ++d) pkr[d] = pkb[(size_t)d * N_ + m];
#pragma unroll
    for (int r = 0; r < 8; ++r) {
      float e = pqr[r][0] * pkr[0];
#pragma unroll
      for (int d = 1; d < D_; ++d) e = fmaf(pqr[r][d], pkr[d], e);
      s[r] += __expf(e);
    }
  }
#pragma unroll
  for (int r = 0; r < 8; ++r) {
    float v = s[r];
    for (int off = 32; off; off >>= 1) v += __shfl_xor(v, off);
    s[r] = v;
  }
  if (lane == 0) {
#pragma unroll
    for (int r = 0; r < 8; ++r) rinv_g[(size_t)b * N_ + r0 + r] = 1.0f / s[r];
  }
}

// ---------------------------------------------------------------------------
// K4 FUSED v4 (8-wave block = 2x wave concurrency): exact round-18 schedule
// (single barrier, implicit DMA wait via pk queue order: pk(t) is issued
// AFTER DMA(t), so the compiler's wait at pk's first use retires DMA(t)),
// but with 512 threads: wave w owns 4 phase-A rows (w*4..+4) and a 32-col
// GEMM slice (c0=w*32) = its own staged pv rows (4 DMAs/iter). Same LDS
// (74KB) -> still 2 blocks/CU but now 16 waves/CU: doubles outstanding NT
// stores and latency hiding (k_attn at 16 waves/CU sustained ~5TB/s).
// ---------------------------------------------------------------------------
__global__ void __launch_bounds__(512, 1) k_fused(
    const float* __restrict__ pq_g, const float* __restrict__ pk_g,
    const float* __restrict__ rinv_g, const unsigned short* __restrict__ pv_g,
    const float* __restrict__ x, const float* __restrict__ gamma,
    float* __restrict__ out_g, float* __restrict__ attn_g) {
  int bx = blockIdx.x;
  int b = bx & 3, grp = bx >> 2;
  int n0 = grp * 32;
  int t = threadIdx.x, lane = t & 63, w = t >> 6;  // w in 0..7
  int rsel = lane & 15, g = lane >> 4, koff = g * 8;
  int c0 = w * 32;            // wave's GEMM c-slice == its staged pv rows
  int r0 = n0 + w * 4;        // phase-A rows for this wave (4)

  __shared__ unsigned short pvs[2][256][64];  // 64KB, slot-swizzled content
  __shared__ unsigned short asl[2][32][72];   // 9KB attn bf16, pad 72

  // per-wave row data: pq rows + rinv (4 rows)
  float pqr[4][D_], rinv[4];
#pragma unroll
  for (int rr = 0; rr < 4; ++rr) {
    const float4* pp = (const float4*)(pq_g + ((size_t)b * N_ + r0 + rr) * D_);
    float4 a = pp[0], c4 = pp[1];
    pqr[rr][0] = a.x; pqr[rr][1] = a.y; pqr[rr][2] = a.z; pqr[rr][3] = a.w;
    pqr[rr][4] = c4.x; pqr[rr][5] = c4.y; pqr[rr][6] = c4.z; pqr[rr][7] = c4.w;
    rinv[rr] = rinv_g[(size_t)b * N_ + r0 + rr];
  }

  const float* pkb = pk_g + (size_t)b * D_ * N_;
  const unsigned short* pvb = pv_g + (size_t)b * C_ * N_;
  float* attb = attn_g + ((size_t)b * N_ + r0) * N_;

  f32x4 acc[2][2];
#pragma unroll
  for (int mf = 0; mf < 2; ++mf)
#pragma unroll
    for (int cf = 0; cf < 2; ++cf) acc[mf][cf] = (f32x4)0.f;

  // pv staging: wave w's 32 c-rows; LDS linear, source XOR-swizzled (verified)
#define STAGEPV(dstbuf, M0)                                                   \
  {                                                                           \
    _Pragma("unroll")                                                         \
    for (int i = 0; i < 4; ++i) {                                             \
      int c = c0 + i * 8 + (lane >> 3);                                       \
      int seg = lane & 7;                                                     \
      g2l16(pvb + (size_t)c * N_ + (M0) + ((seg ^ (c & 7)) << 3),             \
            &pvs[dstbuf][c0 + i * 8][0]);                                     \
    }                                                                         \
  }

  // prologue: tile 0 pv DMAs + tile 0 pk regs (pk AFTER DMA -> queue order)
  STAGEPV(0, 0)
  float pkr[D_];
#pragma unroll
  for (int d = 0; d < D_; ++d) pkr[d] = pkb[(size_t)d * N_ + lane];

  int cur = 0;
  for (int tt = 0; tt < 64; ++tt) {
    int m0 = tt * 64;
    bool more = (tt + 1 < 64);
    // ---- issue tile t+1: pv DMAs then pk reg loads ----
    if (more) STAGEPV(cur ^ 1, m0 + 64)
    float pkn[D_];
    if (more) {
#pragma unroll
      for (int d = 0; d < D_; ++d) pkn[d] = pkb[(size_t)d * N_ + m0 + 64 + lane];
    }
    // ---- phase A: attn rows r0..+4 at m=m0+lane (pk wait drains DMA(t)) ----
#pragma unroll
    for (int rr = 0; rr < 4; ++rr) {
      float e = pqr[rr][0] * pkr[0];
#pragma unroll
      for (int d = 1; d < D_; ++d) e = fmaf(pqr[rr][d], pkr[d], e);
      float a = __expf(e) * rinv[rr];
      __builtin_nontemporal_store(a, attb + (size_t)rr * N_ + m0 + lane);
      asl[cur][w * 4 + rr][lane] = f2bf(a);
    }
    // publish asl writes to the block, then one barrier
    asm volatile("s_waitcnt lgkmcnt(0)" ::: "memory");
    __builtin_amdgcn_s_barrier();
    // ---- MFMA: 32 n x 32 c over K=64 from asl[cur] + pvs[cur] ----
    {
      U16 afr[2][2], bfr[2][2];
#pragma unroll
      for (int kf = 0; kf < 2; ++kf) {
#pragma unroll
        for (int mf = 0; mf < 2; ++mf)
          afr[kf][mf].q = *(const uint4*)&asl[cur][mf * 16 + rsel][kf * 32 + koff];
#pragma unroll
        for (int cf = 0; cf < 2; ++cf) {
          int c = c0 + cf * 16 + rsel;
          int sg = kf * 4 + g;
          bfr[kf][cf].q = *(const uint4*)&pvs[cur][c][(sg ^ (c & 7)) * 8];
        }
      }
#pragma unroll
      for (int kf = 0; kf < 2; ++kf)
#pragma unroll
        for (int mf = 0; mf < 2; ++mf)
#pragma unroll
          for (int cf = 0; cf < 2; ++cf)
            acc[mf][cf] = __builtin_amdgcn_mfma_f32_16x16x32_bf16(
                afr[kf][mf].v, bfr[kf][cf].v, acc[mf][cf], 0, 0, 0);
    }
#pragma unroll
    for (int d = 0; d < D_; ++d) pkr[d] = pkn[d];
    cur ^= 1;
  }
#undef STAGEPV
  // epilogue: out = gamma*acc + x.  D layout: col(lane&15)=c-frag, row=g*4+j
  float gm = gamma[0];
  int rowsub = g * 4;
#pragma unroll
  for (int mf = 0; mf < 2; ++mf) {
#pragma unroll
    for (int cf = 0; cf < 2; ++cf) {
      int c = c0 + cf * 16 + rsel;
      int nrow = n0 + mf * 16 + rowsub;
      const float4 xv = *(const float4*)(x + ((size_t)(b * C_ + c)) * N_ + nrow);
      float4 o;
      o.x = gm * acc[mf][cf][0] + xv.x;
      o.y = gm * acc[mf][cf][1] + xv.y;
      o.z = gm * acc[mf][cf][2] + xv.z;
      o.w = gm * acc[mf][cf][3] + xv.w;
      *(float4*)(out_g + ((size_t)(b * C_ + c)) * N_ + nrow) = o;
    }
  }
}

extern "C" void kernel_launch(void* const* d_in, const int* in_sizes, int n_in,
                              void* d_out, int out_size, void* d_ws, size_t ws_size,
                              hipStream_t stream) {
  const float* x  = (const float*)d_in[0];
  const float* k  = (const float*)d_in[1];
  const float* q  = (const float*)d_in[2];
  const float* Wq = (const float*)d_in[3];
  const float* bq = (const float*)d_in[4];
  const float* Wk = (const float*)d_in[5];
  const float* bk = (const float*)d_in[6];
  const float* Wv = (const float*)d_in[7];
  const float* bv = (const float*)d_in[8];
  const float* gamma = (const float*)d_in[9];

  float* out_g  = (float*)d_out;
  float* attn_g = out_g + (size_t)B_ * C_ * N_;  // attention starts after out

  // workspace layout (~9.2 MB): pq 512KB | pk 512KB | rinv 64KB | pv 8MB
  char* ws = (char*)d_ws;
  float* pq_g = (float*)ws;
  float* pk_g = (float*)(ws + (1u << 19));
  float* rinv_g = (float*)(ws + (1u << 20));
  unsigned short* pv_g = (unsigned short*)(ws + (1u << 20) + (1u << 17));

  k_pqk<<<dim3(64, B_), 256, 0, stream>>>(q, k, Wq, bq, Wk, bk, pq_g, pk_g);
  k_pv<<<dim3(64, B_), 256, 0, stream>>>(x, Wv, bv, pv_g);
  k_rowsum<<<dim3(128, B_), 256, 0, stream>>>(pq_g, pk_g, rinv_g);
  k_fused<<<dim3(512), 512, 0, stream>>>(pq_g, pk_g, rinv_g, pv_g, x, gamma, out_g, attn_g);
}